// Round 3
// baseline (447.142 us; speedup 1.0000x reference)
//
#include <hip/hip_runtime.h>
#include <hip/hip_bf16.h>

typedef __bf16 bf16x8 __attribute__((ext_vector_type(8)));
typedef float  f32x4  __attribute__((ext_vector_type(4)));

#define MFMA_B16(a, b, c) __builtin_amdgcn_mfma_f32_16x16x32_bf16((a), (b), (c), 0, 0, 0)

static constexpr int Bk  = 4;
static constexpr int Sk  = 1024;
static constexpr int Dk  = 1024;
static constexpr int Hk  = 16;
static constexpr int DHk = 64;

// ws layout (__bf16 elements)
static constexpr size_t QH_OFF = 0;                 // [64][1024][64]
static constexpr size_t K_OFF  = 4194304;           // [64][1024][64]
static constexpr size_t VT_OFF = 8388608;           // [64][64][1024]
static constexpr size_t WT_OFF = 12582912;          // [3][1024][1024]
static constexpr size_t ER_OFF = 15728640;          // [1024][64]
static constexpr size_t WS_ELEMS = 15794176;

// ---------------- prep: W -> Wt (bf16, transposed), Er -> bf16 ----------------
__global__ void prep_kernel(const float* __restrict__ Wq, const float* __restrict__ Wk,
                            const float* __restrict__ Wv, const float* __restrict__ Er,
                            __bf16* __restrict__ wt, __bf16* __restrict__ erb)
{
    __shared__ float tile[64][65];
    const int z = blockIdx.z;
    const int tid = threadIdx.x;
    if (z == 3) {
        int idx = (blockIdx.y * 16 + blockIdx.x) * 256 + tid;   // 0..65535
        erb[idx] = (__bf16)Er[idx];
        return;
    }
    const float* W = (z == 0) ? Wq : (z == 1 ? Wk : Wv);
    __bf16* dst = wt + (size_t)z * Dk * Dk;
    const int k0 = blockIdx.y * 64, n0 = blockIdx.x * 64;
    #pragma unroll
    for (int j = 0; j < 16; ++j) {
        int idx = tid + j * 256; int r = idx >> 6, c = idx & 63;
        tile[r][c] = W[(size_t)(k0 + r) * Dk + n0 + c];
    }
    __syncthreads();
    #pragma unroll
    for (int j = 0; j < 16; ++j) {
        int idx = tid + j * 256; int r = idx >> 6, c = idx & 63;
        dst[(size_t)(n0 + r) * Dk + k0 + c] = (__bf16)tile[c][r];   // Wt[n][k] = W[k][n]
    }
}

// ---------------- projections: out = X @ W + b (bf16 MFMA) ----------------
__global__ __launch_bounds__(256) void proj_kernel(
    const float* __restrict__ Xq, const float* __restrict__ Xkv,
    const float* __restrict__ bq, const float* __restrict__ bk,
    const float* __restrict__ bv, const __bf16* __restrict__ wt,
    __bf16* __restrict__ qh, __bf16* __restrict__ kws, __bf16* __restrict__ vt)
{
    __shared__ __align__(16) __bf16 tl[64][72];
    const int z = blockIdx.z;
    const float* X    = (z == 0) ? Xq : Xkv;
    const float* bias = (z == 0) ? bq : (z == 1 ? bk : bv);
    const __bf16* W = wt + (size_t)z * Dk * Dk;

    const int m0 = blockIdx.x * 64;
    const int n0 = blockIdx.y * 64;
    const int lane = threadIdx.x & 63;
    const int w    = threadIdx.x >> 6;
    const int l15  = lane & 15;
    const int g    = lane >> 4;

    const float* xrow = X + (size_t)(m0 + w * 16 + l15) * Dk;
    const f32x4 fz = {0.f, 0.f, 0.f, 0.f};
    f32x4 acc[4];
    #pragma unroll
    for (int j = 0; j < 4; ++j) acc[j] = fz;

    for (int k0 = 0; k0 < Dk; k0 += 32) {
        const int k = k0 + g * 8;
        float4 a0 = *(const float4*)(xrow + k);
        float4 a1 = *(const float4*)(xrow + k + 4);
        bf16x8 a;
        a[0] = (__bf16)a0.x; a[1] = (__bf16)a0.y; a[2] = (__bf16)a0.z; a[3] = (__bf16)a0.w;
        a[4] = (__bf16)a1.x; a[5] = (__bf16)a1.y; a[6] = (__bf16)a1.z; a[7] = (__bf16)a1.w;
        #pragma unroll
        for (int j = 0; j < 4; ++j) {
            bf16x8 bfr = *(const bf16x8*)(W + (size_t)(n0 + j * 16 + l15) * Dk + k);
            acc[j] = MFMA_B16(a, bfr, acc[j]);
        }
    }

    // bias (per output column)
    #pragma unroll
    for (int j = 0; j < 4; ++j) {
        float bb = bias[n0 + j * 16 + l15];
        #pragma unroll
        for (int r = 0; r < 4; ++r) acc[j][r] += bb;
    }

    const int b   = m0 >> 10;        // 64 | 1024, tile within one batch
    const int s0t = m0 & 1023;
    const int h   = n0 >> 6;         // 64-wide tile == one head

    if (z < 2) {
        __bf16* dst = (z == 0) ? qh : kws;
        #pragma unroll
        for (int j = 0; j < 4; ++j) {
            #pragma unroll
            for (int r = 0; r < 4; ++r) {
                int s  = s0t + w * 16 + g * 4 + r;
                int dh = j * 16 + l15;
                dst[((size_t)(b * Hk + h) * Sk + s) * DHk + dh] = (__bf16)acc[j][r];
            }
        }
    } else {
        // transpose tile in LDS, write V^T [bh][dh][s]
        #pragma unroll
        for (int j = 0; j < 4; ++j)
            #pragma unroll
            for (int r = 0; r < 4; ++r)
                tl[j * 16 + l15][w * 16 + g * 4 + r] = (__bf16)acc[j][r];
        __syncthreads();
        int dh = threadIdx.x >> 2, c0 = (threadIdx.x & 3) * 16;
        __bf16* dst = vt + ((size_t)(b * Hk + h) * DHk + dh) * Sk + s0t + c0;
        #pragma unroll
        for (int i = 0; i < 16; ++i) dst[i] = tl[dh][c0 + i];
    }
}

// ---------------- fused causal attention with relative-position band ----------------
__global__ __launch_bounds__(256) void attn_kernel(
    const __bf16* __restrict__ qh, const __bf16* __restrict__ kws,
    const __bf16* __restrict__ vt, const __bf16* __restrict__ erb,
    float* __restrict__ out)
{
    __shared__ __align__(16) float  G_lds[4][16][84];
    __shared__ __align__(16) __bf16 P_lds[4][16][88];

    const int lane = threadIdx.x & 63;
    const int w    = threadIdx.x >> 6;
    const int l15  = lane & 15;
    const int g    = lane >> 4;
    const int bh   = blockIdx.y;
    const int b    = bh >> 4, h = bh & 15;
    const int sw   = blockIdx.x * 64 + w * 16;   // this wave's 16 q-rows

    const __bf16* qbase = qh  + ((size_t)bh * Sk + sw) * DHk;
    const __bf16* kbase = kws + (size_t)bh * Sk * DHk;
    const __bf16* vbase = vt  + (size_t)bh * DHk * Sk;

    bf16x8 aq[2];
    aq[0] = *(const bf16x8*)(qbase + l15 * DHk + g * 8);
    aq[1] = *(const bf16x8*)(qbase + l15 * DHk + 32 + g * 8);

    const f32x4 fz = {0.f, 0.f, 0.f, 0.f};
    f32x4 O[4];
    float m_[4], l_[4];
    #pragma unroll
    for (int n = 0; n < 4; ++n) O[n] = fz;
    #pragma unroll
    for (int r = 0; r < 4; ++r) { m_[r] = -1e30f; l_[r] = 0.f; }

    const int ntw = ((sw + 15) >> 6) + 1;        // causal tile count for this wave

    for (int it = 0; it < ntw; ++it) {
        const int t0 = it * 64;

        // ---- QK^T ----
        f32x4 sc[4];
        #pragma unroll
        for (int j = 0; j < 4; ++j) sc[j] = fz;
        #pragma unroll
        for (int kt = 0; kt < 2; ++kt) {
            #pragma unroll
            for (int j = 0; j < 4; ++j) {
                bf16x8 kb = *(const bf16x8*)(kbase + (size_t)(t0 + j * 16 + l15) * DHk + kt * 32 + g * 8);
                sc[j] = MFMA_B16(aq[kt], kb, sc[j]);
            }
        }

        // ---- G = Q @ Er^T over the 80-wide diagonal band ----
        const int jbase = t0 - sw + 1008;        // 16-aligned, >= 0
        f32x4 gf[5];
        #pragma unroll
        for (int jj = 0; jj < 5; ++jj) gf[jj] = fz;
        #pragma unroll
        for (int kt = 0; kt < 2; ++kt) {
            #pragma unroll
            for (int jj = 0; jj < 5; ++jj) {
                int jrow = jbase + jj * 16 + l15;
                jrow = (jrow > 1023) ? 1023 : jrow;    // clamped rows are masked later
                bf16x8 be = *(const bf16x8*)(erb + (size_t)jrow * DHk + kt * 32 + g * 8);
                gf[jj] = MFMA_B16(aq[kt], be, gf[jj]);
            }
        }
        #pragma unroll
        for (int jj = 0; jj < 5; ++jj)
            #pragma unroll
            for (int r = 0; r < 4; ++r)
                G_lds[w][g * 4 + r][jj * 16 + l15] = gf[jj][r];
        __builtin_amdgcn_sched_barrier(0);       // wave-internal LDS exchange; DS is in-order

        // ---- skew-add Srel, scale, causal mask ----
        #pragma unroll
        for (int j = 0; j < 4; ++j) {
            #pragma unroll
            for (int r = 0; r < 4; ++r) {
                int rr = g * 4 + r;
                int cg = j * 16 + l15;
                float v = (sc[j][r] + G_lds[w][rr][cg - rr + 15]) * 0.125f;
                int t = t0 + cg, s = sw + rr;
                sc[j][r] = (t > s) ? -1e30f : v;
            }
        }

        // ---- online softmax (row lives across 16 lanes of this group) ----
        #pragma unroll
        for (int r = 0; r < 4; ++r) {
            float mt = fmaxf(fmaxf(sc[0][r], sc[1][r]), fmaxf(sc[2][r], sc[3][r]));
            #pragma unroll
            for (int off = 1; off < 16; off <<= 1) mt = fmaxf(mt, __shfl_xor(mt, off));
            float mnew = fmaxf(m_[r], mt);
            float scl  = __expf(m_[r] - mnew);
            float rsum = 0.f;
            #pragma unroll
            for (int j = 0; j < 4; ++j) {
                float p = __expf(sc[j][r] - mnew);
                sc[j][r] = p; rsum += p;
            }
            #pragma unroll
            for (int off = 1; off < 16; off <<= 1) rsum += __shfl_xor(rsum, off);
            l_[r] = l_[r] * scl + rsum;
            m_[r] = mnew;
            #pragma unroll
            for (int n = 0; n < 4; ++n) O[n][r] *= scl;
        }

        // ---- P -> LDS (D-layout -> A-layout exchange) ----
        #pragma unroll
        for (int j = 0; j < 4; ++j)
            #pragma unroll
            for (int r = 0; r < 4; ++r)
                P_lds[w][g * 4 + r][j * 16 + l15] = (__bf16)sc[j][r];
        __builtin_amdgcn_sched_barrier(0);

        // ---- PV ----
        #pragma unroll
        for (int kt = 0; kt < 2; ++kt) {
            bf16x8 pa = *(const bf16x8*)(&P_lds[w][l15][kt * 32 + g * 8]);
            #pragma unroll
            for (int n = 0; n < 4; ++n) {
                bf16x8 vb = *(const bf16x8*)(vbase + (size_t)(n * 16 + l15) * Sk + t0 + kt * 32 + g * 8);
                O[n] = MFMA_B16(pa, vb, O[n]);
            }
        }
    }

    // ---- normalize + write out [b][s][h*64+dh] ----
    float* obase = out + ((size_t)b * Sk + sw) * Dk + h * DHk;
    #pragma unroll
    for (int r = 0; r < 4; ++r) {
        float inv = 1.f / l_[r];
        #pragma unroll
        for (int n = 0; n < 4; ++n)
            obase[(size_t)(g * 4 + r) * Dk + n * 16 + l15] = O[n][r] * inv;
    }
}

extern "C" void kernel_launch(void* const* d_in, const int* in_sizes, int n_in,
                              void* d_out, int out_size, void* d_ws, size_t ws_size,
                              hipStream_t stream)
{
    const float* q  = (const float*)d_in[0];
    const float* kv = (const float*)d_in[1];
    const float* Wq = (const float*)d_in[2];
    const float* bq = (const float*)d_in[3];
    const float* Wk = (const float*)d_in[4];
    const float* bk = (const float*)d_in[5];
    const float* Wv = (const float*)d_in[6];
    const float* bv = (const float*)d_in[7];
    const float* Er = (const float*)d_in[8];
    float* out = (float*)d_out;

    if (ws_size < WS_ELEMS * sizeof(__bf16)) return;
    __bf16* ws  = (__bf16*)d_ws;
    __bf16* qh  = ws + QH_OFF;
    __bf16* kws = ws + K_OFF;
    __bf16* vt  = ws + VT_OFF;
    __bf16* wt  = ws + WT_OFF;
    __bf16* erb = ws + ER_OFF;

    prep_kernel<<<dim3(16, 16, 4), 256, 0, stream>>>(Wq, Wk, Wv, Er, wt, erb);
    proj_kernel<<<dim3(64, 16, 3), 256, 0, stream>>>(q, kv, bq, bk, bv, wt, qh, kws, vt);
    attn_kernel<<<dim3(16, 64), 256, 0, stream>>>(qh, kws, vt, erb, out);
}

// Round 4
// 229.894 us; speedup vs baseline: 1.9450x; 1.9450x over previous
//
#include <hip/hip_runtime.h>
#include <hip/hip_bf16.h>

typedef __bf16 bf16x8 __attribute__((ext_vector_type(8)));
typedef __bf16 bf16x4 __attribute__((ext_vector_type(4)));
typedef float  f32x4  __attribute__((ext_vector_type(4)));

#define MFMA_B16(a, b, c) __builtin_amdgcn_mfma_f32_16x16x32_bf16((a), (b), (c), 0, 0, 0)

static constexpr int Bk  = 4;
static constexpr int Sk  = 1024;
static constexpr int Dk  = 1024;
static constexpr int Hk  = 16;
static constexpr int DHk = 64;

// ws layout (__bf16 elements)
static constexpr size_t QH_OFF = 0;                 // [64][1024][64]
static constexpr size_t K_OFF  = 4194304;           // [64][1024][64]
static constexpr size_t VT_OFF = 8388608;           // [64][64][1024]
static constexpr size_t WT_OFF = 12582912;          // [3][1024][1024]
static constexpr size_t ER_OFF = 15728640;          // [1024][64]
static constexpr size_t WS_ELEMS = 15794176;

__device__ __forceinline__ void load_lds16(const void* g, void* l) {
    __builtin_amdgcn_global_load_lds((const __attribute__((address_space(1))) void*)g,
                                     (__attribute__((address_space(3))) void*)l, 16, 0, 0);
}

// ---------------- prep: W -> Wt (bf16, transposed), Er -> bf16 ----------------
__global__ void prep_kernel(const float* __restrict__ Wq, const float* __restrict__ Wk,
                            const float* __restrict__ Wv, const float* __restrict__ Er,
                            __bf16* __restrict__ wt, __bf16* __restrict__ erb)
{
    __shared__ float tile[64][65];
    const int z = blockIdx.z;
    const int tid = threadIdx.x;
    if (z == 3) {
        int idx = (blockIdx.y * 16 + blockIdx.x) * 256 + tid;   // 0..65535
        erb[idx] = (__bf16)Er[idx];
        return;
    }
    const float* W = (z == 0) ? Wq : (z == 1 ? Wk : Wv);
    __bf16* dst = wt + (size_t)z * Dk * Dk;
    const int k0 = blockIdx.y * 64, n0 = blockIdx.x * 64;
    #pragma unroll
    for (int j = 0; j < 16; ++j) {
        int idx = tid + j * 256; int r = idx >> 6, c = idx & 63;
        tile[r][c] = W[(size_t)(k0 + r) * Dk + n0 + c];
    }
    __syncthreads();
    #pragma unroll
    for (int j = 0; j < 16; ++j) {
        int idx = tid + j * 256; int r = idx >> 6, c = idx & 63;
        dst[(size_t)(n0 + r) * Dk + k0 + c] = (__bf16)tile[c][r];   // Wt[n][k] = W[k][n]
    }
}

// ---------------- projections: m97-style 128x128 tile, BK=32, global_load_lds ----------------
// A (f32) LDS [128][32] : 128B rows -> XOR slot-swizzle  slot' = slot ^ (row&7)   (16B slots)
// B (bf16) LDS [128][32]: 64B rows  -> XOR slot-swizzle  slot' = slot ^ ((row>>1)&3)
// Both applied as: linear LDS dest + inverse-swizzled GLOBAL source + swizzled ds_read (rule #21).
__global__ __launch_bounds__(256) void proj_kernel(
    const float* __restrict__ Xq, const float* __restrict__ Xkv,
    const float* __restrict__ bq, const float* __restrict__ bk,
    const float* __restrict__ bv, const __bf16* __restrict__ wt,
    __bf16* __restrict__ qh, __bf16* __restrict__ kws, __bf16* __restrict__ vt)
{
    __shared__ __align__(16) float  Al[128 * 32];
    __shared__ __align__(16) __bf16 Bl[128 * 32];

    const int z = blockIdx.z;
    const float* X    = (z == 0) ? Xq : Xkv;
    const float* bias = (z == 0) ? bq : (z == 1 ? bk : bv);
    const __bf16* Wz  = wt + (size_t)z * Dk * Dk;

    const int m0   = blockIdx.x * 128;
    const int n0   = blockIdx.y * 128;
    const int tid  = threadIdx.x;
    const int lane = tid & 63;
    const int w    = tid >> 6;
    const int wr   = w >> 1, wc = w & 1;
    const int l15  = lane & 15;
    const int g    = lane >> 4;

    // ---- staging source pointers (per-lane, pre-swizzled global source) ----
    // A: chunk c = w*4+i covers rows c*8 .. c*8+7 (8 slots of 16B per 128B row)
    //    lane -> row = c*8 + (lane>>3), lds slot = lane&7, data col-slot = (lane&7)^(lane>>3)
    const float* asrc[4];
    int adst[4];
    #pragma unroll
    for (int i = 0; i < 4; ++i) {
        const int c = w * 4 + i;
        asrc[i] = X + (size_t)(m0 + c * 8 + (lane >> 3)) * Dk + (((lane & 7) ^ (lane >> 3)) << 2);
        adst[i] = c * 1024 + lane * 16;          // bytes
    }
    // B: chunk c = w*2+i covers rows c*16 .. c*16+15 (4 slots per 64B row)
    //    lane -> row = c*16 + (lane>>2), lds slot = lane&3, data col-slot = (lane&3)^((lane>>3)&3)
    const __bf16* bsrc[2];
    int bdst[2];
    #pragma unroll
    for (int i = 0; i < 2; ++i) {
        const int c = w * 2 + i;
        bsrc[i] = Wz + (size_t)(n0 + c * 16 + (lane >> 2)) * Dk + (((lane & 3) ^ ((lane >> 3) & 3)) << 3);
        bdst[i] = c * 1024 + lane * 16;          // bytes
    }

    // ---- fragment read offsets (bytes, swizzled) ----
    int aoff0[4], aoff1[4], boff[4];
    #pragma unroll
    for (int m = 0; m < 4; ++m) {
        const int row = wr * 64 + m * 16 + l15;          // row&7 == l15&7
        aoff0[m] = row * 128 + (((2 * g)     ^ (l15 & 7)) << 4);
        aoff1[m] = row * 128 + (((2 * g + 1) ^ (l15 & 7)) << 4);
    }
    #pragma unroll
    for (int n = 0; n < 4; ++n) {
        const int row = wc * 64 + n * 16 + l15;          // (row>>1)&3 == (l15>>1)&3
        boff[n] = row * 64 + ((g ^ ((l15 >> 1) & 3)) << 4);
    }

    const f32x4 fz = {0.f, 0.f, 0.f, 0.f};
    f32x4 acc[4][4];
    #pragma unroll
    for (int m = 0; m < 4; ++m)
        #pragma unroll
        for (int n = 0; n < 4; ++n) acc[m][n] = fz;

    const char* Alc = (const char*)Al;
    const char* Blc = (const char*)Bl;

    for (int ks = 0; ks < Dk / 32; ++ks) {
        // ---- async stage A (16KB) + B (8KB) ----
        #pragma unroll
        for (int i = 0; i < 4; ++i)
            load_lds16(asrc[i], (char*)Al + adst[i]);
        #pragma unroll
        for (int i = 0; i < 2; ++i)
            load_lds16(bsrc[i], (char*)Bl + bdst[i]);
        #pragma unroll
        for (int i = 0; i < 4; ++i) asrc[i] += 32;
        #pragma unroll
        for (int i = 0; i < 2; ++i) bsrc[i] += 32;
        __syncthreads();                                  // compiler drains vmcnt before barrier

        // ---- fragments ----
        bf16x8 bf[4];
        #pragma unroll
        for (int n = 0; n < 4; ++n)
            bf[n] = *(const bf16x8*)(Blc + boff[n]);
        bf16x8 af[4];
        #pragma unroll
        for (int m = 0; m < 4; ++m) {
            f32x4 x0 = *(const f32x4*)(Alc + aoff0[m]);
            f32x4 x1 = *(const f32x4*)(Alc + aoff1[m]);
            bf16x8 a;
            a[0] = (__bf16)x0[0]; a[1] = (__bf16)x0[1]; a[2] = (__bf16)x0[2]; a[3] = (__bf16)x0[3];
            a[4] = (__bf16)x1[0]; a[5] = (__bf16)x1[1]; a[6] = (__bf16)x1[2]; a[7] = (__bf16)x1[3];
            af[m] = a;
        }

        // ---- 16 MFMA ----
        #pragma unroll
        for (int m = 0; m < 4; ++m)
            #pragma unroll
            for (int n = 0; n < 4; ++n)
                acc[m][n] = MFMA_B16(af[m], bf[n], acc[m][n]);
        __syncthreads();
    }

    // ---- bias ----
    #pragma unroll
    for (int n = 0; n < 4; ++n) {
        const float bb = bias[n0 + wc * 64 + n * 16 + l15];
        #pragma unroll
        for (int m = 0; m < 4; ++m)
            #pragma unroll
            for (int r = 0; r < 4; ++r) acc[m][n][r] += bb;
    }

    // ---- epilogue ----
    const int b   = m0 >> 10;                    // 128-row tile sits within one batch
    const int s0t = (m0 & 1023) + wr * 64;
    const int h   = (n0 + wc * 64) >> 6;         // one head per wave column

    if (z < 2) {
        __bf16* dst = (z == 0) ? qh : kws;
        const size_t rowbase = (size_t)(b * Hk + h) * Sk;
        #pragma unroll
        for (int m = 0; m < 4; ++m) {
            #pragma unroll
            for (int r = 0; r < 4; ++r) {
                const int s = s0t + m * 16 + g * 4 + r;
                __bf16* drow = dst + (rowbase + s) * DHk;
                #pragma unroll
                for (int n = 0; n < 4; ++n)
                    drow[n * 16 + l15] = (__bf16)acc[m][n][r];
            }
        }
    } else {
        // V^T [bh][dh][s]: pack 4 consecutive-s values -> one 8B store
        const size_t hb = (size_t)(b * Hk + h) * DHk;
        #pragma unroll
        for (int m = 0; m < 4; ++m) {
            const int sb = s0t + m * 16 + g * 4;
            #pragma unroll
            for (int n = 0; n < 4; ++n) {
                const int dh = n * 16 + l15;
                bf16x4 pk;
                #pragma unroll
                for (int r = 0; r < 4; ++r) pk[r] = (__bf16)acc[m][n][r];
                *(bf16x4*)(vt + (hb + dh) * Sk + sb) = pk;
            }
        }
    }
}

// ---------------- fused causal attention with relative-position band ----------------
__global__ __launch_bounds__(256) void attn_kernel(
    const __bf16* __restrict__ qh, const __bf16* __restrict__ kws,
    const __bf16* __restrict__ vt, const __bf16* __restrict__ erb,
    float* __restrict__ out)
{
    __shared__ __align__(16) float  G_lds[4][16][84];
    __shared__ __align__(16) __bf16 P_lds[4][16][88];

    const int lane = threadIdx.x & 63;
    const int w    = threadIdx.x >> 6;
    const int l15  = lane & 15;
    const int g    = lane >> 4;
    const int bh   = blockIdx.y;
    const int b    = bh >> 4, h = bh & 15;
    const int sw   = blockIdx.x * 64 + w * 16;   // this wave's 16 q-rows

    const __bf16* qbase = qh  + ((size_t)bh * Sk + sw) * DHk;
    const __bf16* kbase = kws + (size_t)bh * Sk * DHk;
    const __bf16* vbase = vt  + (size_t)bh * DHk * Sk;

    bf16x8 aq[2];
    aq[0] = *(const bf16x8*)(qbase + l15 * DHk + g * 8);
    aq[1] = *(const bf16x8*)(qbase + l15 * DHk + 32 + g * 8);

    const f32x4 fz = {0.f, 0.f, 0.f, 0.f};
    f32x4 O[4];
    float m_[4], l_[4];
    #pragma unroll
    for (int n = 0; n < 4; ++n) O[n] = fz;
    #pragma unroll
    for (int r = 0; r < 4; ++r) { m_[r] = -1e30f; l_[r] = 0.f; }

    const int ntw = ((sw + 15) >> 6) + 1;        // causal tile count for this wave

    for (int it = 0; it < ntw; ++it) {
        const int t0 = it * 64;

        // ---- QK^T ----
        f32x4 sc[4];
        #pragma unroll
        for (int j = 0; j < 4; ++j) sc[j] = fz;
        #pragma unroll
        for (int kt = 0; kt < 2; ++kt) {
            #pragma unroll
            for (int j = 0; j < 4; ++j) {
                bf16x8 kb = *(const bf16x8*)(kbase + (size_t)(t0 + j * 16 + l15) * DHk + kt * 32 + g * 8);
                sc[j] = MFMA_B16(aq[kt], kb, sc[j]);
            }
        }

        // ---- G = Q @ Er^T over the 80-wide diagonal band ----
        const int jbase = t0 - sw + 1008;        // 16-aligned, >= 0
        f32x4 gf[5];
        #pragma unroll
        for (int jj = 0; jj < 5; ++jj) gf[jj] = fz;
        #pragma unroll
        for (int kt = 0; kt < 2; ++kt) {
            #pragma unroll
            for (int jj = 0; jj < 5; ++jj) {
                int jrow = jbase + jj * 16 + l15;
                jrow = (jrow > 1023) ? 1023 : jrow;    // clamped rows are masked later
                bf16x8 be = *(const bf16x8*)(erb + (size_t)jrow * DHk + kt * 32 + g * 8);
                gf[jj] = MFMA_B16(aq[kt], be, gf[jj]);
            }
        }
        #pragma unroll
        for (int jj = 0; jj < 5; ++jj)
            #pragma unroll
            for (int r = 0; r < 4; ++r)
                G_lds[w][g * 4 + r][jj * 16 + l15] = gf[jj][r];
        __builtin_amdgcn_sched_barrier(0);       // wave-internal LDS exchange; DS is in-order

        // ---- skew-add Srel, scale, causal mask ----
        #pragma unroll
        for (int j = 0; j < 4; ++j) {
            #pragma unroll
            for (int r = 0; r < 4; ++r) {
                int rr = g * 4 + r;
                int cg = j * 16 + l15;
                float v = (sc[j][r] + G_lds[w][rr][cg - rr + 15]) * 0.125f;
                int t = t0 + cg, s = sw + rr;
                sc[j][r] = (t > s) ? -1e30f : v;
            }
        }

        // ---- online softmax (row lives across 16 lanes of this group) ----
        #pragma unroll
        for (int r = 0; r < 4; ++r) {
            float mt = fmaxf(fmaxf(sc[0][r], sc[1][r]), fmaxf(sc[2][r], sc[3][r]));
            #pragma unroll
            for (int off = 1; off < 16; off <<= 1) mt = fmaxf(mt, __shfl_xor(mt, off));
            float mnew = fmaxf(m_[r], mt);
            float scl  = __expf(m_[r] - mnew);
            float rsum = 0.f;
            #pragma unroll
            for (int j = 0; j < 4; ++j) {
                float p = __expf(sc[j][r] - mnew);
                sc[j][r] = p; rsum += p;
            }
            #pragma unroll
            for (int off = 1; off < 16; off <<= 1) rsum += __shfl_xor(rsum, off);
            l_[r] = l_[r] * scl + rsum;
            m_[r] = mnew;
            #pragma unroll
            for (int n = 0; n < 4; ++n) O[n][r] *= scl;
        }

        // ---- P -> LDS (D-layout -> A-layout exchange) ----
        #pragma unroll
        for (int j = 0; j < 4; ++j)
            #pragma unroll
            for (int r = 0; r < 4; ++r)
                P_lds[w][g * 4 + r][j * 16 + l15] = (__bf16)sc[j][r];
        __builtin_amdgcn_sched_barrier(0);

        // ---- PV ----
        #pragma unroll
        for (int kt = 0; kt < 2; ++kt) {
            bf16x8 pa = *(const bf16x8*)(&P_lds[w][l15][kt * 32 + g * 8]);
            #pragma unroll
            for (int n = 0; n < 4; ++n) {
                bf16x8 vb = *(const bf16x8*)(vbase + (size_t)(n * 16 + l15) * Sk + t0 + kt * 32 + g * 8);
                O[n] = MFMA_B16(pa, vb, O[n]);
            }
        }
    }

    // ---- normalize + write out [b][s][h*64+dh] ----
    float* obase = out + ((size_t)b * Sk + sw) * Dk + h * DHk;
    #pragma unroll
    for (int r = 0; r < 4; ++r) {
        float inv = 1.f / l_[r];
        #pragma unroll
        for (int n = 0; n < 4; ++n)
            obase[(size_t)(g * 4 + r) * Dk + n * 16 + l15] = O[n][r] * inv;
    }
}

extern "C" void kernel_launch(void* const* d_in, const int* in_sizes, int n_in,
                              void* d_out, int out_size, void* d_ws, size_t ws_size,
                              hipStream_t stream)
{
    const float* q  = (const float*)d_in[0];
    const float* kv = (const float*)d_in[1];
    const float* Wq = (const float*)d_in[2];
    const float* bq = (const float*)d_in[3];
    const float* Wk = (const float*)d_in[4];
    const float* bk = (const float*)d_in[5];
    const float* Wv = (const float*)d_in[6];
    const float* bv = (const float*)d_in[7];
    const float* Er = (const float*)d_in[8];
    float* out = (float*)d_out;

    if (ws_size < WS_ELEMS * sizeof(__bf16)) return;
    __bf16* ws  = (__bf16*)d_ws;
    __bf16* qh  = ws + QH_OFF;
    __bf16* kws = ws + K_OFF;
    __bf16* vt  = ws + VT_OFF;
    __bf16* wt  = ws + WT_OFF;
    __bf16* erb = ws + ER_OFF;

    prep_kernel<<<dim3(16, 16, 4), 256, 0, stream>>>(Wq, Wk, Wv, Er, wt, erb);
    proj_kernel<<<dim3(32, 8, 3), 256, 0, stream>>>(q, kv, bq, bk, bv, wt, qh, kws, vt);
    attn_kernel<<<dim3(16, 64), 256, 0, stream>>>(qh, kws, vt, erb, out);
}

// Round 5
// 151.957 us; speedup vs baseline: 2.9426x; 1.5129x over previous
//
#include <hip/hip_runtime.h>
#include <hip/hip_bf16.h>

typedef __bf16 bf16x8 __attribute__((ext_vector_type(8)));
typedef __bf16 bf16x4 __attribute__((ext_vector_type(4)));
typedef float  f32x4  __attribute__((ext_vector_type(4)));

#define MFMA_B16(a, b, c) __builtin_amdgcn_mfma_f32_16x16x32_bf16((a), (b), (c), 0, 0, 0)

static constexpr int Bk  = 4;
static constexpr int Sk  = 1024;
static constexpr int Dk  = 1024;
static constexpr int Hk  = 16;
static constexpr int DHk = 64;

// ws layout (__bf16 elements)
static constexpr size_t QH_OFF = 0;                 // [64][1024][64]
static constexpr size_t K_OFF  = 4194304;           // [64][1024][64]
static constexpr size_t VT_OFF = 8388608;           // [64][64][1024]
static constexpr size_t WT_OFF = 12582912;          // [3][1024][1024]
static constexpr size_t ER_OFF = 15728640;          // [1024][64]
static constexpr size_t WS_ELEMS = 15794176;

__device__ __forceinline__ void load_lds16(const void* g, void* l) {
    __builtin_amdgcn_global_load_lds((const __attribute__((address_space(1))) void*)g,
                                     (__attribute__((address_space(3))) void*)l, 16, 0, 0);
}

// ---------------- prep: W -> Wt (bf16, transposed), Er -> bf16 ----------------
__global__ void prep_kernel(const float* __restrict__ Wq, const float* __restrict__ Wk,
                            const float* __restrict__ Wv, const float* __restrict__ Er,
                            __bf16* __restrict__ wt, __bf16* __restrict__ erb)
{
    __shared__ float tile[64][65];
    const int z = blockIdx.z;
    const int tid = threadIdx.x;
    if (z == 3) {
        int idx = (blockIdx.y * 16 + blockIdx.x) * 256 + tid;   // 0..65535
        erb[idx] = (__bf16)Er[idx];
        return;
    }
    const float* W = (z == 0) ? Wq : (z == 1 ? Wk : Wv);
    __bf16* dst = wt + (size_t)z * Dk * Dk;
    const int k0 = blockIdx.y * 64, n0 = blockIdx.x * 64;
    #pragma unroll
    for (int j = 0; j < 16; ++j) {
        int idx = tid + j * 256; int r = idx >> 6, c = idx & 63;
        tile[r][c] = W[(size_t)(k0 + r) * Dk + n0 + c];
    }
    __syncthreads();
    #pragma unroll
    for (int j = 0; j < 16; ++j) {
        int idx = tid + j * 256; int r = idx >> 6, c = idx & 63;
        dst[(size_t)(n0 + r) * Dk + k0 + c] = (__bf16)tile[c][r];   // Wt[n][k] = W[k][n]
    }
}

// ---------------- projections: m97-style 128x128 tile, BK=32, global_load_lds ----------------
__global__ __launch_bounds__(256) void proj_kernel(
    const float* __restrict__ Xq, const float* __restrict__ Xkv,
    const float* __restrict__ bq, const float* __restrict__ bk,
    const float* __restrict__ bv, const __bf16* __restrict__ wt,
    __bf16* __restrict__ qh, __bf16* __restrict__ kws, __bf16* __restrict__ vt)
{
    __shared__ __align__(16) float  Al[128 * 32];
    __shared__ __align__(16) __bf16 Bl[128 * 32];

    const int z = blockIdx.z;
    const float* X    = (z == 0) ? Xq : Xkv;
    const float* bias = (z == 0) ? bq : (z == 1 ? bk : bv);
    const __bf16* Wz  = wt + (size_t)z * Dk * Dk;

    const int m0   = blockIdx.x * 128;
    const int n0   = blockIdx.y * 128;
    const int tid  = threadIdx.x;
    const int lane = tid & 63;
    const int w    = tid >> 6;
    const int wr   = w >> 1, wc = w & 1;
    const int l15  = lane & 15;
    const int g    = lane >> 4;

    const float* asrc[4];
    int adst[4];
    #pragma unroll
    for (int i = 0; i < 4; ++i) {
        const int c = w * 4 + i;
        asrc[i] = X + (size_t)(m0 + c * 8 + (lane >> 3)) * Dk + (((lane & 7) ^ (lane >> 3)) << 2);
        adst[i] = c * 1024 + lane * 16;          // bytes
    }
    const __bf16* bsrc[2];
    int bdst[2];
    #pragma unroll
    for (int i = 0; i < 2; ++i) {
        const int c = w * 2 + i;
        bsrc[i] = Wz + (size_t)(n0 + c * 16 + (lane >> 2)) * Dk + (((lane & 3) ^ ((lane >> 3) & 3)) << 3);
        bdst[i] = c * 1024 + lane * 16;          // bytes
    }

    int aoff0[4], aoff1[4], boff[4];
    #pragma unroll
    for (int m = 0; m < 4; ++m) {
        const int row = wr * 64 + m * 16 + l15;          // row&7 == l15&7
        aoff0[m] = row * 128 + (((2 * g)     ^ (l15 & 7)) << 4);
        aoff1[m] = row * 128 + (((2 * g + 1) ^ (l15 & 7)) << 4);
    }
    #pragma unroll
    for (int n = 0; n < 4; ++n) {
        const int row = wc * 64 + n * 16 + l15;          // (row>>1)&3 == (l15>>1)&3
        boff[n] = row * 64 + ((g ^ ((l15 >> 1) & 3)) << 4);
    }

    const f32x4 fz = {0.f, 0.f, 0.f, 0.f};
    f32x4 acc[4][4];
    #pragma unroll
    for (int m = 0; m < 4; ++m)
        #pragma unroll
        for (int n = 0; n < 4; ++n) acc[m][n] = fz;

    const char* Alc = (const char*)Al;
    const char* Blc = (const char*)Bl;

    for (int ks = 0; ks < Dk / 32; ++ks) {
        #pragma unroll
        for (int i = 0; i < 4; ++i)
            load_lds16(asrc[i], (char*)Al + adst[i]);
        #pragma unroll
        for (int i = 0; i < 2; ++i)
            load_lds16(bsrc[i], (char*)Bl + bdst[i]);
        #pragma unroll
        for (int i = 0; i < 4; ++i) asrc[i] += 32;
        #pragma unroll
        for (int i = 0; i < 2; ++i) bsrc[i] += 32;
        __syncthreads();

        bf16x8 bf[4];
        #pragma unroll
        for (int n = 0; n < 4; ++n)
            bf[n] = *(const bf16x8*)(Blc + boff[n]);
        bf16x8 af[4];
        #pragma unroll
        for (int m = 0; m < 4; ++m) {
            f32x4 x0 = *(const f32x4*)(Alc + aoff0[m]);
            f32x4 x1 = *(const f32x4*)(Alc + aoff1[m]);
            bf16x8 a;
            a[0] = (__bf16)x0[0]; a[1] = (__bf16)x0[1]; a[2] = (__bf16)x0[2]; a[3] = (__bf16)x0[3];
            a[4] = (__bf16)x1[0]; a[5] = (__bf16)x1[1]; a[6] = (__bf16)x1[2]; a[7] = (__bf16)x1[3];
            af[m] = a;
        }

        #pragma unroll
        for (int m = 0; m < 4; ++m)
            #pragma unroll
            for (int n = 0; n < 4; ++n)
                acc[m][n] = MFMA_B16(af[m], bf[n], acc[m][n]);
        __syncthreads();
    }

    #pragma unroll
    for (int n = 0; n < 4; ++n) {
        const float bb = bias[n0 + wc * 64 + n * 16 + l15];
        #pragma unroll
        for (int m = 0; m < 4; ++m)
            #pragma unroll
            for (int r = 0; r < 4; ++r) acc[m][n][r] += bb;
    }

    const int b   = m0 >> 10;
    const int s0t = (m0 & 1023) + wr * 64;
    const int h   = (n0 + wc * 64) >> 6;

    if (z < 2) {
        __bf16* dst = (z == 0) ? qh : kws;
        const size_t rowbase = (size_t)(b * Hk + h) * Sk;
        #pragma unroll
        for (int m = 0; m < 4; ++m) {
            #pragma unroll
            for (int r = 0; r < 4; ++r) {
                const int s = s0t + m * 16 + g * 4 + r;
                __bf16* drow = dst + (rowbase + s) * DHk;
                #pragma unroll
                for (int n = 0; n < 4; ++n)
                    drow[n * 16 + l15] = (__bf16)acc[m][n][r];
            }
        }
    } else {
        const size_t hb = (size_t)(b * Hk + h) * DHk;
        #pragma unroll
        for (int m = 0; m < 4; ++m) {
            const int sb = s0t + m * 16 + g * 4;
            #pragma unroll
            for (int n = 0; n < 4; ++n) {
                const int dh = n * 16 + l15;
                bf16x4 pk;
                #pragma unroll
                for (int r = 0; r < 4; ++r) pk[r] = (__bf16)acc[m][n][r];
                *(bf16x4*)(vt + (hb + dh) * Sk + sb) = pk;
            }
        }
    }
}

// ---------------- fused causal attention with relative-position band ----------------
// One strip = 64 q-rows (4 waves x 16). Each block processes strip xp and strip 15-xp
// -> uniform 17 tile-steps per wave across the whole grid (no tail).
// K/V/Er fragments are register-prefetched one tile ahead (load-behind pipeline).
__device__ __forceinline__ void attn_strip(
    const __bf16* __restrict__ qh, const __bf16* __restrict__ kbase,
    const __bf16* __restrict__ vbase, const __bf16* __restrict__ erb,
    float* __restrict__ out, float (*Gw)[84], __bf16 (*Pw)[88],
    int bh, int sw, int ntw, int l15, int g)
{
    const __bf16* qbase = qh + ((size_t)bh * Sk + sw) * DHk;
    bf16x8 aq[2];
    aq[0] = *(const bf16x8*)(qbase + l15 * DHk + g * 8);
    aq[1] = *(const bf16x8*)(qbase + l15 * DHk + 32 + g * 8);

    const f32x4 fz = {0.f, 0.f, 0.f, 0.f};
    f32x4 O[4];
    float m_[4], l_[4];
    #pragma unroll
    for (int n = 0; n < 4; ++n) O[n] = fz;
    #pragma unroll
    for (int r = 0; r < 4; ++r) { m_[r] = -1e30f; l_[r] = 0.f; }

    // ---- preload tile-0 fragments ----
    bf16x8 kc[8], vc[8], ec[10];
    {
        const int jb0 = 1008 - sw;
        #pragma unroll
        for (int kt = 0; kt < 2; ++kt) {
            #pragma unroll
            for (int j = 0; j < 4; ++j)
                kc[kt * 4 + j] = *(const bf16x8*)(kbase + (size_t)(j * 16 + l15) * DHk + kt * 32 + g * 8);
            #pragma unroll
            for (int n = 0; n < 4; ++n)
                vc[kt * 4 + n] = *(const bf16x8*)(vbase + (size_t)(n * 16 + l15) * Sk + kt * 32 + g * 8);
            #pragma unroll
            for (int jj = 0; jj < 5; ++jj) {
                int jr = jb0 + jj * 16 + l15;
                jr = (jr > 1023) ? 1023 : jr;
                ec[kt * 5 + jj] = *(const bf16x8*)(erb + (size_t)jr * DHk + kt * 32 + g * 8);
            }
        }
    }

    for (int it = 0; it < ntw; ++it) {
        const int t0 = it * 64;
        const int tn = (it + 1 < ntw ? it + 1 : it) * 64;   // clamped prefetch tile

        // ---- QK^T ----
        f32x4 sc[4];
        #pragma unroll
        for (int j = 0; j < 4; ++j) sc[j] = fz;
        __builtin_amdgcn_s_setprio(1);
        #pragma unroll
        for (int kt = 0; kt < 2; ++kt)
            #pragma unroll
            for (int j = 0; j < 4; ++j)
                sc[j] = MFMA_B16(aq[kt], kc[kt * 4 + j], sc[j]);
        __builtin_amdgcn_s_setprio(0);
        // prefetch K for next tile (issue-early, use next iter)
        #pragma unroll
        for (int kt = 0; kt < 2; ++kt)
            #pragma unroll
            for (int j = 0; j < 4; ++j)
                kc[kt * 4 + j] = *(const bf16x8*)(kbase + (size_t)(tn + j * 16 + l15) * DHk + kt * 32 + g * 8);

        // ---- G = Q @ Er^T over the 80-wide diagonal band ----
        f32x4 gf[5];
        #pragma unroll
        for (int jj = 0; jj < 5; ++jj) gf[jj] = fz;
        __builtin_amdgcn_s_setprio(1);
        #pragma unroll
        for (int kt = 0; kt < 2; ++kt)
            #pragma unroll
            for (int jj = 0; jj < 5; ++jj)
                gf[jj] = MFMA_B16(aq[kt], ec[kt * 5 + jj], gf[jj]);
        __builtin_amdgcn_s_setprio(0);
        // prefetch Er for next tile
        {
            const int jbn = tn - sw + 1008;
            #pragma unroll
            for (int kt = 0; kt < 2; ++kt)
                #pragma unroll
                for (int jj = 0; jj < 5; ++jj) {
                    int jr = jbn + jj * 16 + l15;
                    jr = (jr > 1023) ? 1023 : jr;
                    ec[kt * 5 + jj] = *(const bf16x8*)(erb + (size_t)jr * DHk + kt * 32 + g * 8);
                }
        }

        #pragma unroll
        for (int jj = 0; jj < 5; ++jj)
            #pragma unroll
            for (int r = 0; r < 4; ++r)
                Gw[g * 4 + r][jj * 16 + l15] = gf[jj][r];
        __builtin_amdgcn_sched_barrier(0);

        // ---- skew-add Srel, scale, causal mask ----
        #pragma unroll
        for (int j = 0; j < 4; ++j) {
            #pragma unroll
            for (int r = 0; r < 4; ++r) {
                int rr = g * 4 + r;
                int cg = j * 16 + l15;
                float v = (sc[j][r] + Gw[rr][cg - rr + 15]) * 0.125f;
                int t = t0 + cg, s = sw + rr;
                sc[j][r] = (t > s) ? -1e30f : v;
            }
        }

        // ---- online softmax ----
        #pragma unroll
        for (int r = 0; r < 4; ++r) {
            float mt = fmaxf(fmaxf(sc[0][r], sc[1][r]), fmaxf(sc[2][r], sc[3][r]));
            #pragma unroll
            for (int off = 1; off < 16; off <<= 1) mt = fmaxf(mt, __shfl_xor(mt, off));
            float mnew = fmaxf(m_[r], mt);
            float scl  = __expf(m_[r] - mnew);
            float rsum = 0.f;
            #pragma unroll
            for (int j = 0; j < 4; ++j) {
                float p = __expf(sc[j][r] - mnew);
                sc[j][r] = p; rsum += p;
            }
            #pragma unroll
            for (int off = 1; off < 16; off <<= 1) rsum += __shfl_xor(rsum, off);
            l_[r] = l_[r] * scl + rsum;
            m_[r] = mnew;
            #pragma unroll
            for (int n = 0; n < 4; ++n) O[n][r] *= scl;
        }

        // ---- P -> LDS (D-layout -> A-layout exchange) ----
        #pragma unroll
        for (int j = 0; j < 4; ++j)
            #pragma unroll
            for (int r = 0; r < 4; ++r)
                Pw[g * 4 + r][j * 16 + l15] = (__bf16)sc[j][r];
        __builtin_amdgcn_sched_barrier(0);

        // ---- PV ----
        __builtin_amdgcn_s_setprio(1);
        #pragma unroll
        for (int kt = 0; kt < 2; ++kt) {
            bf16x8 pa = *(const bf16x8*)(&Pw[l15][kt * 32 + g * 8]);
            #pragma unroll
            for (int n = 0; n < 4; ++n)
                O[n] = MFMA_B16(pa, vc[kt * 4 + n], O[n]);
        }
        __builtin_amdgcn_s_setprio(0);
        // prefetch V for next tile
        #pragma unroll
        for (int kt = 0; kt < 2; ++kt)
            #pragma unroll
            for (int n = 0; n < 4; ++n)
                vc[kt * 4 + n] = *(const bf16x8*)(vbase + (size_t)(n * 16 + l15) * Sk + tn + kt * 32 + g * 8);
    }

    // ---- normalize + write out [b][s][h*64+dh] ----
    const int b = bh >> 4, h = bh & 15;
    float* obase = out + ((size_t)b * Sk + sw) * Dk + h * DHk;
    #pragma unroll
    for (int r = 0; r < 4; ++r) {
        float inv = 1.f / l_[r];
        #pragma unroll
        for (int n = 0; n < 4; ++n)
            obase[(size_t)(g * 4 + r) * Dk + n * 16 + l15] = O[n][r] * inv;
    }
}

__global__ __launch_bounds__(256, 2) void attn_kernel(
    const __bf16* __restrict__ qh, const __bf16* __restrict__ kws,
    const __bf16* __restrict__ vt, const __bf16* __restrict__ erb,
    float* __restrict__ out)
{
    __shared__ __align__(16) float  G_lds[4][16][84];
    __shared__ __align__(16) __bf16 P_lds[4][16][88];

    const int lane = threadIdx.x & 63;
    const int w    = threadIdx.x >> 6;
    const int l15  = lane & 15;
    const int g    = lane >> 4;

    const int lid = blockIdx.x;
    const int bh  = lid & 63;        // lid%8 == bh%8 -> one bh's blocks share an XCD
    const int xp  = lid >> 6;        // 0..7: strip pair (xp, 15-xp), uniform 17 tiles

    const __bf16* kbase = kws + (size_t)bh * Sk * DHk;
    const __bf16* vbase = vt  + (size_t)bh * DHk * Sk;

    attn_strip(qh, kbase, vbase, erb, out, G_lds[w], P_lds[w],
               bh, xp * 64 + w * 16, xp + 1, l15, g);
    attn_strip(qh, kbase, vbase, erb, out, G_lds[w], P_lds[w],
               bh, (15 - xp) * 64 + w * 16, 16 - xp, l15, g);
}

extern "C" void kernel_launch(void* const* d_in, const int* in_sizes, int n_in,
                              void* d_out, int out_size, void* d_ws, size_t ws_size,
                              hipStream_t stream)
{
    const float* q  = (const float*)d_in[0];
    const float* kv = (const float*)d_in[1];
    const float* Wq = (const float*)d_in[2];
    const float* bq = (const float*)d_in[3];
    const float* Wk = (const float*)d_in[4];
    const float* bk = (const float*)d_in[5];
    const float* Wv = (const float*)d_in[6];
    const float* bv = (const float*)d_in[7];
    const float* Er = (const float*)d_in[8];
    float* out = (float*)d_out;

    if (ws_size < WS_ELEMS * sizeof(__bf16)) return;
    __bf16* ws  = (__bf16*)d_ws;
    __bf16* qh  = ws + QH_OFF;
    __bf16* kws = ws + K_OFF;
    __bf16* vt  = ws + VT_OFF;
    __bf16* wt  = ws + WT_OFF;
    __bf16* erb = ws + ER_OFF;

    prep_kernel<<<dim3(16, 16, 4), 256, 0, stream>>>(Wq, Wk, Wv, Er, wt, erb);
    proj_kernel<<<dim3(32, 8, 3), 256, 0, stream>>>(q, kv, bq, bk, bv, wt, qh, kws, vt);
    attn_kernel<<<dim3(512), 256, 0, stream>>>(qh, kws, vt, erb, out);
}